// Round 2
// baseline (242.038 us; speedup 1.0000x reference)
//
#include <hip/hip_runtime.h>
#include <hip/hip_bf16.h>

#define CCH   512
#define BATCH 8
#define NPOS  1024
#define MQKV  1536
#define SCALE 0.125f
#define EPS   1e-5f

typedef __attribute__((ext_vector_type(4))) float f32x4;
typedef __attribute__((ext_vector_type(8))) __bf16 bf16x8;
typedef __attribute__((ext_vector_type(8))) unsigned short u16x8;

__device__ inline unsigned short f2bf(float f) {
  __hip_bfloat16 h = __float2bfloat16(f);
  return __builtin_bit_cast(unsigned short, h);
}
__device__ inline float bf2f(unsigned short u) {
  return __bfloat162float(__builtin_bit_cast(__hip_bfloat16, u));
}

// ---------------- 1. weights fp32 -> bf16 ----------------
__global__ void prep_weights(const float* __restrict__ wq, const float* __restrict__ wo,
                             unsigned short* __restrict__ wqb, unsigned short* __restrict__ wob) {
  int i = blockIdx.x * 256 + threadIdx.x;
  if (i < MQKV * CCH) wqb[i] = f2bf(wq[i]);
  if (i < CCH * CCH)  wob[i] = f2bf(wo[i]);
}

// ---------------- 2. CPB table: [8][63][63] ----------------
__global__ void cpb_table(const float* __restrict__ w0, const float* __restrict__ b0,
                          const float* __restrict__ w1, const float* __restrict__ b1,
                          const float* __restrict__ w2, const float* __restrict__ b2,
                          float* __restrict__ table) {
  __shared__ float sh1[128];
  __shared__ float sh2[128];
  int d0 = blockIdx.x;               // 0..3968
  int dy = d0 / 63 - 31, dx = d0 % 63 - 31;
  float r0 = (dy > 0 ? 1.f : (dy < 0 ? -1.f : 0.f)) * logf(fabsf((float)dy) + 1.f);
  float r1 = (dx > 0 ? 1.f : (dx < 0 ? -1.f : 0.f)) * logf(fabsf((float)dx) + 1.f);
  int t = threadIdx.x;               // 128
  float h0 = r0 * w0[t * 2 + 0] + r1 * w0[t * 2 + 1] + b0[t];
  sh1[t] = (h0 >= 0.f) ? h0 : 0.1f * h0;
  __syncthreads();
  float a = b1[t];
  #pragma unroll 8
  for (int c = 0; c < 128; ++c) a += sh1[c] * w1[t * 128 + c];
  sh2[t] = (a >= 0.f) ? a : 0.1f * a;
  __syncthreads();
  if (t < 8) {
    float o = b2[t];
    #pragma unroll 8
    for (int c = 0; c < 128; ++c) o += sh2[c] * w2[t * 128 + c];
    table[t * 3969 + d0] = o;
  }
}

// ---------------- 3. expand bias to [8][1024][1024] bf16 ----------------
__global__ void bias_expand(const float* __restrict__ table, unsigned short* __restrict__ biasF) {
  int idx = blockIdx.x * 256 + threadIdx.x;   // 8*1024*1024 total
  int h = idx >> 20;
  int i = (idx >> 10) & 1023;
  int j = idx & 1023;
  int dy = (i >> 5) - (j >> 5) + 31;
  int dx = (i & 31) - (j & 31) + 31;
  biasF[idx] = f2bf(table[h * 3969 + dy * 63 + dx]);
}

// ---------------- 4. channel LayerNorm -> xnT [8192][512] bf16 ----------------
__global__ __launch_bounds__(256) void ln_kernel(const float* __restrict__ x,
                                                 const float* __restrict__ gamma,
                                                 unsigned short* __restrict__ xnT) {
  int t = threadIdx.x;
  int gpos = blockIdx.x * 32 + (t >> 3);      // global position 0..8191
  int b = gpos >> 10, p = gpos & 1023;
  int cl = t & 7;
  const float* xp = x + (size_t)b * CCH * NPOS + p;
  float vals[64];
  float s1 = 0.f, s2 = 0.f;
  #pragma unroll
  for (int j = 0; j < 64; ++j) {
    float v = xp[(size_t)(cl * 64 + j) * NPOS];
    vals[j] = v; s1 += v; s2 += v * v;
  }
  #pragma unroll
  for (int m = 1; m < 8; m <<= 1) { s1 += __shfl_xor(s1, m, 64); s2 += __shfl_xor(s2, m, 64); }
  float mean = s1 * (1.f / 512.f);
  float var = s2 * (1.f / 512.f) - mean * mean;
  float rstd = rsqrtf(var + EPS);
  unsigned short outv[64];
  #pragma unroll
  for (int j = 0; j < 64; ++j) {
    int c = cl * 64 + j;
    outv[j] = f2bf((vals[j] - mean) * rstd * gamma[c]);
  }
  unsigned short* op = xnT + (size_t)gpos * 512 + cl * 64;
  #pragma unroll
  for (int j = 0; j < 8; ++j) *(u16x8*)(op + j * 8) = *(const u16x8*)(outv + j * 8);
}

// ---------------- 5. GEMM C = A * B^T, A[M][512], B[N][512] bf16 ----------------
// MODE 0: qkv epilogue (scatter to qT/kT/vB).  MODE 1: out proj + residual -> f32.
template <int MODE>
__global__ __launch_bounds__(256) void gemm_bt(const unsigned short* __restrict__ Ag,
                                               const unsigned short* __restrict__ Bg,
                                               unsigned short* __restrict__ qT,
                                               unsigned short* __restrict__ kT,
                                               unsigned short* __restrict__ vB,
                                               const float* __restrict__ xres,
                                               float* __restrict__ yout) {
  __shared__ unsigned short As[128 * 64];
  __shared__ unsigned short Bs[128 * 64];
  int tid = threadIdx.x;
  int m0 = blockIdx.y * 128, nn0 = blockIdx.x * 128;
  int wave = tid >> 6, lane = tid & 63;
  int wm = wave >> 1, wn = wave & 1;
  int l16 = lane & 15, lh = lane >> 4;
  f32x4 acc[4][4];
  #pragma unroll
  for (int it = 0; it < 4; ++it)
    #pragma unroll
    for (int jt = 0; jt < 4; ++jt) acc[it][jt] = (f32x4){0.f, 0.f, 0.f, 0.f};

  for (int k0 = 0; k0 < 512; k0 += 64) {
    #pragma unroll
    for (int r = 0; r < 4; ++r) {
      int li = r * 2048 + tid * 8;
      int row = li >> 6, col = li & 63;
      *(u16x8*)&As[li] = *(const u16x8*)&Ag[(size_t)(m0 + row) * 512 + k0 + col];
      *(u16x8*)&Bs[li] = *(const u16x8*)&Bg[(size_t)(nn0 + row) * 512 + k0 + col];
    }
    __syncthreads();
    #pragma unroll
    for (int ks = 0; ks < 2; ++ks) {
      int koff = ks * 32 + lh * 8;
      bf16x8 a[4], b[4];
      #pragma unroll
      for (int it = 0; it < 4; ++it) a[it] = *(const bf16x8*)&As[(wm * 64 + it * 16 + l16) * 64 + koff];
      #pragma unroll
      for (int jt = 0; jt < 4; ++jt) b[jt] = *(const bf16x8*)&Bs[(wn * 64 + jt * 16 + l16) * 64 + koff];
      #pragma unroll
      for (int it = 0; it < 4; ++it)
        #pragma unroll
        for (int jt = 0; jt < 4; ++jt)
          acc[it][jt] = __builtin_amdgcn_mfma_f32_16x16x32_bf16(a[it], b[jt], acc[it][jt], 0, 0, 0);
    }
    __syncthreads();
  }

  #pragma unroll
  for (int it = 0; it < 4; ++it) {
    int mbase = m0 + wm * 64 + it * 16 + lh * 4;
    #pragma unroll
    for (int jt = 0; jt < 4; ++jt) {
      int nn = nn0 + wn * 64 + jt * 16 + l16;
      #pragma unroll
      for (int r = 0; r < 4; ++r) {
        int m = mbase + r;
        float v = acc[it][jt][r];
        if (MODE == 0) {
          int sel = m >> 9, hd = m & 511;
          int hh = hd >> 6, d = hd & 63;
          int bb = nn >> 10, p = nn & 1023;
          int bh = bb * 8 + hh;
          if (sel == 0)      qT[((size_t)bh * 1024 + p) * 64 + d] = f2bf(v);
          else if (sel == 1) kT[((size_t)bh * 1024 + p) * 64 + d] = f2bf(v);
          else               vB[((size_t)bh * 64 + d) * 1024 + p] = f2bf(v);
        } else {
          int bb = nn >> 10, p = nn & 1023;
          size_t addr = ((size_t)bb * 512 + m) * 1024 + p;
          yout[addr] = v + xres[addr];
        }
      }
    }
  }
}

// ---------------- 6. flash attention per (b,h), 128 q-rows per block ----------------
__global__ __launch_bounds__(256) void attn_kernel(const unsigned short* __restrict__ qT,
                                                   const unsigned short* __restrict__ kT,
                                                   const unsigned short* __restrict__ vB,
                                                   const unsigned short* __restrict__ biasF,
                                                   unsigned short* __restrict__ attnout) {
  __shared__ unsigned short Qs[128 * 64];
  __shared__ unsigned short Ks[64 * 64];
  __shared__ unsigned short Vs[64 * 64];
  __shared__ unsigned short Ps[4][32 * 64];
  int tid = threadIdx.x;
  int i0 = blockIdx.x * 128;
  int bh = blockIdx.y;
  int hh = bh & 7, bb = bh >> 3;
  int w = tid >> 6, lane = tid & 63, l16 = lane & 15, lh = lane >> 4;
  const unsigned short* qbase = qT + (size_t)bh * NPOS * 64;
  const unsigned short* kbase = kT + (size_t)bh * NPOS * 64;
  const unsigned short* vbase = vB + (size_t)bh * 64 * NPOS;

  #pragma unroll
  for (int r = 0; r < 4; ++r) {
    int li = r * 2048 + tid * 8;
    int row = li >> 6, col = li & 63;
    *(u16x8*)&Qs[li] = *(const u16x8*)&qbase[(size_t)(i0 + row) * 64 + col];
  }

  f32x4 o[2][4];
  float m_s[8], l_s[8];
  #pragma unroll
  for (int it = 0; it < 2; ++it)
    #pragma unroll
    for (int dt = 0; dt < 4; ++dt) o[it][dt] = (f32x4){0.f, 0.f, 0.f, 0.f};
  #pragma unroll
  for (int r = 0; r < 8; ++r) { m_s[r] = -1e30f; l_s[r] = 0.f; }

  for (int j0 = 0; j0 < 1024; j0 += 64) {
    #pragma unroll
    for (int r = 0; r < 2; ++r) {
      int li = r * 2048 + tid * 8;
      int row = li >> 6, col = li & 63;
      *(u16x8*)&Ks[li] = *(const u16x8*)&kbase[(size_t)(j0 + row) * 64 + col];
      *(u16x8*)&Vs[li] = *(const u16x8*)&vbase[(size_t)row * 1024 + j0 + col];
    }
    __syncthreads();

    f32x4 s[2][4];
    #pragma unroll
    for (int it = 0; it < 2; ++it)
      #pragma unroll
      for (int jt = 0; jt < 4; ++jt) s[it][jt] = (f32x4){0.f, 0.f, 0.f, 0.f};
    #pragma unroll
    for (int ks = 0; ks < 2; ++ks) {
      int koff = ks * 32 + lh * 8;
      bf16x8 aq[2], bk[4];
      #pragma unroll
      for (int it = 0; it < 2; ++it) aq[it] = *(const bf16x8*)&Qs[(w * 32 + it * 16 + l16) * 64 + koff];
      #pragma unroll
      for (int jt = 0; jt < 4; ++jt) bk[jt] = *(const bf16x8*)&Ks[(jt * 16 + l16) * 64 + koff];
      #pragma unroll
      for (int it = 0; it < 2; ++it)
        #pragma unroll
        for (int jt = 0; jt < 4; ++jt)
          s[it][jt] = __builtin_amdgcn_mfma_f32_16x16x32_bf16(aq[it], bk[jt], s[it][jt], 0, 0, 0);
    }

    // online softmax (each output row is owned by the 16-lane group sharing lh)
    #pragma unroll
    for (int it = 0; it < 2; ++it) {
      #pragma unroll
      for (int r = 0; r < 4; ++r) {
        int idx8 = it * 4 + r;
        int rloc = it * 16 + lh * 4 + r;
        int gi = i0 + w * 32 + rloc;
        float sv[4];
        float tmax = -1e30f;
        #pragma unroll
        for (int jt = 0; jt < 4; ++jt) {
          float bias = bf2f(biasF[((size_t)hh * 1024 + gi) * 1024 + j0 + jt * 16 + l16]);
          sv[jt] = s[it][jt][r] * SCALE + bias;
          tmax = fmaxf(tmax, sv[jt]);
        }
        #pragma unroll
        for (int mm = 1; mm < 16; mm <<= 1) tmax = fmaxf(tmax, __shfl_xor(tmax, mm, 64));
        float mnew = fmaxf(m_s[idx8], tmax);
        float corr = __expf(m_s[idx8] - mnew);
        float psum = 0.f;
        #pragma unroll
        for (int jt = 0; jt < 4; ++jt) {
          float pv = __expf(sv[jt] - mnew);
          psum += pv;
          Ps[w][rloc * 64 + jt * 16 + l16] = f2bf(pv);
        }
        // FIX (round 1): reduce the row-sum across the 16-lane group that owns
        // this row — each lane only holds 4 of the 64 columns. Without this,
        // l_s was 1/16 of the true denominator -> outputs ~16x too large.
        #pragma unroll
        for (int mm = 1; mm < 16; mm <<= 1) psum += __shfl_xor(psum, mm, 64);
        l_s[idx8] = l_s[idx8] * corr + psum;
        m_s[idx8] = mnew;
        #pragma unroll
        for (int dt = 0; dt < 4; ++dt) o[it][dt][r] *= corr;
      }
    }
    __syncthreads();   // P visible; also protects Vs before next overwrite

    #pragma unroll
    for (int js = 0; js < 2; ++js) {
      int koff = js * 32 + lh * 8;
      bf16x8 pa[2], vb[4];
      #pragma unroll
      for (int it = 0; it < 2; ++it) pa[it] = *(const bf16x8*)&Ps[w][(it * 16 + l16) * 64 + koff];
      #pragma unroll
      for (int dt = 0; dt < 4; ++dt) vb[dt] = *(const bf16x8*)&Vs[(dt * 16 + l16) * 64 + koff];
      #pragma unroll
      for (int it = 0; it < 2; ++it)
        #pragma unroll
        for (int dt = 0; dt < 4; ++dt)
          o[it][dt] = __builtin_amdgcn_mfma_f32_16x16x32_bf16(pa[it], vb[dt], o[it][dt], 0, 0, 0);
    }
    __syncthreads();
  }

  #pragma unroll
  for (int it = 0; it < 2; ++it)
    #pragma unroll
    for (int r = 0; r < 4; ++r) {
      float inv = 1.f / l_s[it * 4 + r];
      int gi = i0 + w * 32 + it * 16 + lh * 4 + r;
      #pragma unroll
      for (int dt = 0; dt < 4; ++dt)
        attnout[((size_t)bb * 1024 + gi) * 512 + hh * 64 + dt * 16 + l16] = f2bf(o[it][dt][r] * inv);
    }
}

extern "C" void kernel_launch(void* const* d_in, const int* in_sizes, int n_in,
                              void* d_out, int out_size, void* d_ws, size_t ws_size,
                              hipStream_t stream) {
  const float* x     = (const float*)d_in[0];
  const float* gamma = (const float*)d_in[1];
  const float* w_qkv = (const float*)d_in[2];
  const float* w_out = (const float*)d_in[3];
  const float* cw0   = (const float*)d_in[4];
  const float* cb0   = (const float*)d_in[5];
  const float* cw1   = (const float*)d_in[6];
  const float* cb1   = (const float*)d_in[7];
  const float* cw2   = (const float*)d_in[8];
  const float* cb2   = (const float*)d_in[9];
  float* out = (float*)d_out;

  char* ws = (char*)d_ws;
  unsigned short* xnT   = (unsigned short*)(ws + 0);          // 8 MB
  unsigned short* wqb   = (unsigned short*)(ws + 8388608);    // 1.5 MB
  unsigned short* wob   = (unsigned short*)(ws + 9961472);    // 0.5 MB
  unsigned short* qT    = (unsigned short*)(ws + 10485760);   // 8 MB
  unsigned short* kT    = (unsigned short*)(ws + 18874368);   // 8 MB
  unsigned short* vB    = (unsigned short*)(ws + 27262976);   // 8 MB
  float*          table = (float*)(ws + 35651584);            // 128 KB
  unsigned short* biasF = (unsigned short*)(ws + 35782656);   // 16 MB
  unsigned short* aout  = (unsigned short*)(ws + 52559872);   // 8 MB

  prep_weights<<<3072, 256, 0, stream>>>(w_qkv, w_out, wqb, wob);
  cpb_table<<<3969, 128, 0, stream>>>(cw0, cb0, cw1, cb1, cw2, cb2, table);
  bias_expand<<<32768, 256, 0, stream>>>(table, biasF);
  ln_kernel<<<256, 256, 0, stream>>>(x, gamma, xnT);
  gemm_bt<0><<<dim3(64, 12), 256, 0, stream>>>(wqb, xnT, qT, kT, vB, nullptr, nullptr);
  attn_kernel<<<dim3(8, 64), 256, 0, stream>>>(qT, kT, vB, biasF, aout);
  gemm_bt<1><<<dim3(64, 4), 256, 0, stream>>>(wob, aout, nullptr, nullptr, nullptr, x, out);
}

// Round 3
// 174.446 us; speedup vs baseline: 1.3875x; 1.3875x over previous
//
#include <hip/hip_runtime.h>
#include <hip/hip_bf16.h>

#define CCH   512
#define BATCH 8
#define NPOS  1024
#define MQKV  1536
#define EPS   1e-5f

typedef __attribute__((ext_vector_type(4))) float f32x4;
typedef __attribute__((ext_vector_type(8))) __bf16 bf16x8;
typedef __attribute__((ext_vector_type(8))) unsigned short u16x8;
typedef __attribute__((ext_vector_type(4))) unsigned short u16x4;

__device__ inline unsigned short f2bf(float f) {
  __hip_bfloat16 h = __float2bfloat16(f);
  return __builtin_bit_cast(unsigned short, h);
}
__device__ inline float bf2f(unsigned short u) {
  return __bfloat162float(__builtin_bit_cast(__hip_bfloat16, u));
}

// LDS xor-swizzle (T2): ushort index within a [row][64] tile.
// byte ^= (row&7)<<4  ==  ushort col ^= (row&7)<<3. Keeps 16B alignment.
__device__ inline int sw(int row, int col) { return row * 64 + (col ^ ((row & 7) << 3)); }

// ---------------- 1. weights fp32 -> bf16 (q rows pre-scaled by 1/8) ----------------
__global__ void prep_weights(const float* __restrict__ wq, const float* __restrict__ wo,
                             unsigned short* __restrict__ wqb, unsigned short* __restrict__ wob) {
  int i = blockIdx.x * 256 + threadIdx.x;
  if (i < MQKV * CCH) {
    float v = wq[i];
    if (i < 512 * CCH) v *= 0.125f;   // fold DIM_HEAD^-0.5 into q projection (exact: 2^-3)
    wqb[i] = f2bf(v);
  }
  if (i < CCH * CCH) wob[i] = f2bf(wo[i]);
}

// ---------------- 2. CPB table: [8][63][63] ----------------
__global__ void cpb_table(const float* __restrict__ w0, const float* __restrict__ b0,
                          const float* __restrict__ w1, const float* __restrict__ b1,
                          const float* __restrict__ w2, const float* __restrict__ b2,
                          float* __restrict__ table) {
  __shared__ float sh1[128];
  __shared__ float sh2[128];
  int d0 = blockIdx.x;               // 0..3968
  int dy = d0 / 63 - 31, dx = d0 % 63 - 31;
  float r0 = (dy > 0 ? 1.f : (dy < 0 ? -1.f : 0.f)) * logf(fabsf((float)dy) + 1.f);
  float r1 = (dx > 0 ? 1.f : (dx < 0 ? -1.f : 0.f)) * logf(fabsf((float)dx) + 1.f);
  int t = threadIdx.x;               // 128
  float h0 = r0 * w0[t * 2 + 0] + r1 * w0[t * 2 + 1] + b0[t];
  sh1[t] = (h0 >= 0.f) ? h0 : 0.1f * h0;
  __syncthreads();
  float a = b1[t];
  #pragma unroll 8
  for (int c = 0; c < 128; ++c) a += sh1[c] * w1[t * 128 + c];
  sh2[t] = (a >= 0.f) ? a : 0.1f * a;
  __syncthreads();
  if (t < 8) {
    float o = b2[t];
    #pragma unroll 8
    for (int c = 0; c < 128; ++c) o += sh2[c] * w2[t * 128 + c];
    table[t * 3969 + d0] = o;
  }
}

// ---------------- 3. expand bias, fragment-permuted: [h][i][jtile(16)][l16*4+jt] ----------------
// element (h,i,j) with j = jtile*64 + jt*16 + l16 stored at ((h*1024+i)*16+jtile)*64 + l16*4+jt
__global__ void bias_expand(const float* __restrict__ table, unsigned short* __restrict__ biasP) {
  int idx = blockIdx.x * 256 + threadIdx.x;   // 8*1024*1024 total, idx == output address
  int h = idx >> 20;
  int i = (idx >> 10) & 1023;
  int blk = (idx >> 6) & 15;
  int q = idx & 63;
  int l16 = q >> 2, jt = q & 3;
  int j = blk * 64 + jt * 16 + l16;
  int dy = (i >> 5) - (j >> 5) + 31;
  int dx = (i & 31) - (j & 31) + 31;
  biasP[idx] = f2bf(table[h * 3969 + dy * 63 + dx]);
}

// ---------------- 4. channel LayerNorm -> xnT [8192][512] bf16 ----------------
__global__ __launch_bounds__(256) void ln_kernel(const float* __restrict__ x,
                                                 const float* __restrict__ gamma,
                                                 unsigned short* __restrict__ xnT) {
  int t = threadIdx.x;
  int gpos = blockIdx.x * 32 + (t >> 3);      // global position 0..8191
  int b = gpos >> 10, p = gpos & 1023;
  int cl = t & 7;
  const float* xp = x + (size_t)b * CCH * NPOS + p;
  float vals[64];
  float s1 = 0.f, s2 = 0.f;
  #pragma unroll
  for (int j = 0; j < 64; ++j) {
    float v = xp[(size_t)(cl * 64 + j) * NPOS];
    vals[j] = v; s1 += v; s2 += v * v;
  }
  #pragma unroll
  for (int m = 1; m < 8; m <<= 1) { s1 += __shfl_xor(s1, m, 64); s2 += __shfl_xor(s2, m, 64); }
  float mean = s1 * (1.f / 512.f);
  float var = s2 * (1.f / 512.f) - mean * mean;
  float rstd = rsqrtf(var + EPS);
  unsigned short outv[64];
  #pragma unroll
  for (int j = 0; j < 64; ++j) {
    int c = cl * 64 + j;
    outv[j] = f2bf((vals[j] - mean) * rstd * gamma[c]);
  }
  unsigned short* op = xnT + (size_t)gpos * 512 + cl * 64;
  #pragma unroll
  for (int j = 0; j < 8; ++j) *(u16x8*)(op + j * 8) = *(const u16x8*)(outv + j * 8);
}

// ---------------- 5. GEMM C = A * B^T, A[M][512], B[N][512] bf16 ----------------
// MODE 0: qkv epilogue (scatter to qT/kT/vB).  MODE 1: out proj + residual -> f32.
template <int MODE>
__global__ __launch_bounds__(256) void gemm_bt(const unsigned short* __restrict__ Ag,
                                               const unsigned short* __restrict__ Bg,
                                               unsigned short* __restrict__ qT,
                                               unsigned short* __restrict__ kT,
                                               unsigned short* __restrict__ vB,
                                               const float* __restrict__ xres,
                                               float* __restrict__ yout) {
  __shared__ unsigned short As[128 * 64];
  __shared__ unsigned short Bs[128 * 64];
  int tid = threadIdx.x;
  int m0 = blockIdx.y * 128, nn0 = blockIdx.x * 128;
  int wave = tid >> 6, lane = tid & 63;
  int wm = wave >> 1, wn = wave & 1;
  int l16 = lane & 15, lh = lane >> 4;
  f32x4 acc[4][4];
  #pragma unroll
  for (int it = 0; it < 4; ++it)
    #pragma unroll
    for (int jt = 0; jt < 4; ++jt) acc[it][jt] = (f32x4){0.f, 0.f, 0.f, 0.f};

  for (int k0 = 0; k0 < 512; k0 += 64) {
    #pragma unroll
    for (int r = 0; r < 4; ++r) {
      int li = r * 2048 + tid * 8;
      int row = li >> 6, col = li & 63;
      *(u16x8*)&As[sw(row, col)] = *(const u16x8*)&Ag[(size_t)(m0 + row) * 512 + k0 + col];
      *(u16x8*)&Bs[sw(row, col)] = *(const u16x8*)&Bg[(size_t)(nn0 + row) * 512 + k0 + col];
    }
    __syncthreads();
    #pragma unroll
    for (int ks = 0; ks < 2; ++ks) {
      int koff = ks * 32 + lh * 8;
      bf16x8 a[4], b[4];
      #pragma unroll
      for (int it = 0; it < 4; ++it) a[it] = *(const bf16x8*)&As[sw(wm * 64 + it * 16 + l16, koff)];
      #pragma unroll
      for (int jt = 0; jt < 4; ++jt) b[jt] = *(const bf16x8*)&Bs[sw(wn * 64 + jt * 16 + l16, koff)];
      #pragma unroll
      for (int it = 0; it < 4; ++it)
        #pragma unroll
        for (int jt = 0; jt < 4; ++jt)
          acc[it][jt] = __builtin_amdgcn_mfma_f32_16x16x32_bf16(a[it], b[jt], acc[it][jt], 0, 0, 0);
    }
    __syncthreads();
  }

  #pragma unroll
  for (int it = 0; it < 4; ++it) {
    int mbase = m0 + wm * 64 + it * 16 + lh * 4;
    #pragma unroll
    for (int jt = 0; jt < 4; ++jt) {
      int nn = nn0 + wn * 64 + jt * 16 + l16;
      #pragma unroll
      for (int r = 0; r < 4; ++r) {
        int m = mbase + r;
        float v = acc[it][jt][r];
        if (MODE == 0) {
          int sel = m >> 9, hd = m & 511;
          int hh = hd >> 6, d = hd & 63;
          int bb = nn >> 10, p = nn & 1023;
          int bh = bb * 8 + hh;
          if (sel == 0)      qT[((size_t)bh * 1024 + p) * 64 + d] = f2bf(v);
          else if (sel == 1) kT[((size_t)bh * 1024 + p) * 64 + d] = f2bf(v);
          else               vB[((size_t)bh * 64 + d) * 1024 + p] = f2bf(v);
        } else {
          int bb = nn >> 10, p = nn & 1023;
          size_t addr = ((size_t)bb * 512 + m) * 1024 + p;
          yout[addr] = v + xres[addr];
        }
      }
    }
  }
}

// ---------------- 6. flash attention per (b,h), 64 q-rows per block, 4 waves ----------------
// wave w owns q-rows [i0 + w*16, +16). Denominator = extra PV accumulator vs ones-column.
__global__ __launch_bounds__(256) void attn_kernel(const unsigned short* __restrict__ qT,
                                                   const unsigned short* __restrict__ kT,
                                                   const unsigned short* __restrict__ vB,
                                                   const unsigned short* __restrict__ biasP,
                                                   unsigned short* __restrict__ attnout) {
  __shared__ unsigned short Qs[64 * 64];
  __shared__ unsigned short Ks[64 * 64];
  __shared__ unsigned short Vs[64 * 64];
  __shared__ unsigned short Ps[4][16 * 64];
  int tid = threadIdx.x;
  int i0 = blockIdx.x * 64;
  int bh = blockIdx.y;
  int hh = bh & 7, bb = bh >> 3;
  int w = tid >> 6, lane = tid & 63, l16 = lane & 15, lh = lane >> 4;
  const unsigned short* qbase = qT + (size_t)bh * NPOS * 64;
  const unsigned short* kbase = kT + (size_t)bh * NPOS * 64;
  const unsigned short* vbase = vB + (size_t)bh * 64 * NPOS;

  #pragma unroll
  for (int r = 0; r < 2; ++r) {
    int li = r * 2048 + tid * 8;
    int row = li >> 6, col = li & 63;
    *(u16x8*)&Qs[sw(row, col)] = *(const u16x8*)&qbase[(size_t)(i0 + row) * 64 + col];
  }

  f32x4 o[5];                       // dt 0..3 = output dims, 4 = softmax denominator
  float m_s[4];
  #pragma unroll
  for (int dt = 0; dt < 5; ++dt) o[dt] = (f32x4){0.f, 0.f, 0.f, 0.f};
  #pragma unroll
  for (int r = 0; r < 4; ++r) m_s[r] = -1e30f;

  bf16x8 ones;
  {
    unsigned short ob = f2bf(1.0f);
    u16x8 tmp = {ob, ob, ob, ob, ob, ob, ob, ob};
    ones = __builtin_bit_cast(bf16x8, tmp);
  }

  for (int j0 = 0; j0 < 1024; j0 += 64) {
    {
      int li = tid * 8;
      int row = li >> 6, col = li & 63;        // rows 0..31 covered; two halves
      *(u16x8*)&Ks[sw(row, col)] = *(const u16x8*)&kbase[(size_t)(j0 + row) * 64 + col];
      *(u16x8*)&Vs[sw(row, col)] = *(const u16x8*)&vbase[(size_t)row * 1024 + j0 + col];
      int row2 = row + 32;
      *(u16x8*)&Ks[sw(row2, col)] = *(const u16x8*)&kbase[(size_t)(j0 + row2) * 64 + col];
      *(u16x8*)&Vs[sw(row2, col)] = *(const u16x8*)&vbase[(size_t)row2 * 1024 + j0 + col];
    }
    __syncthreads();

    // ---- QK^T: s[jt] over 4 j-fragments, K=64 in 2 steps ----
    f32x4 s[4];
    #pragma unroll
    for (int jt = 0; jt < 4; ++jt) s[jt] = (f32x4){0.f, 0.f, 0.f, 0.f};
    #pragma unroll
    for (int ks = 0; ks < 2; ++ks) {
      int koff = ks * 32 + lh * 8;
      int qrow = w * 16 + l16;
      bf16x8 aq = *(const bf16x8*)&Qs[sw(qrow, koff)];
      #pragma unroll
      for (int jt = 0; jt < 4; ++jt) {
        bf16x8 bk = *(const bf16x8*)&Ks[sw(jt * 16 + l16, koff)];
        s[jt] = __builtin_amdgcn_mfma_f32_16x16x32_bf16(aq, bk, s[jt], 0, 0, 0);
      }
    }

    // ---- online softmax: each lane owns rows rloc = lh*4+r of this wave's 16 ----
    #pragma unroll
    for (int r = 0; r < 4; ++r) {
      int rloc = lh * 4 + r;
      int gi = i0 + w * 16 + rloc;
      u16x4 bv = *(const u16x4*)&biasP[(((size_t)hh * 1024 + gi) * 16 + (j0 >> 6)) * 64 + l16 * 4];
      float sv[4];
      float tmax = -1e30f;
      #pragma unroll
      for (int jt = 0; jt < 4; ++jt) {
        sv[jt] = s[jt][r] + bf2f(bv[jt]);
        tmax = fmaxf(tmax, sv[jt]);
      }
      #pragma unroll
      for (int mm = 1; mm < 16; mm <<= 1) tmax = fmaxf(tmax, __shfl_xor(tmax, mm, 64));
      float mnew = fmaxf(m_s[r], tmax);
      float corr = __expf(m_s[r] - mnew);
      m_s[r] = mnew;
      #pragma unroll
      for (int jt = 0; jt < 4; ++jt)
        Ps[w][sw(rloc, jt * 16 + l16)] = f2bf(__expf(sv[jt] - mnew));
      #pragma unroll
      for (int dt = 0; dt < 5; ++dt) o[dt][r] *= corr;
    }
    // Ps[w] is wave-private: no barrier needed before PV.

    // ---- PV: o[dt] += P * V^T[dt], o[4] += P * 1 (denominator) ----
    #pragma unroll
    for (int js = 0; js < 2; ++js) {
      int koff = js * 32 + lh * 8;
      bf16x8 pa = *(const bf16x8*)&Ps[w][sw(l16, koff)];
      #pragma unroll
      for (int dt = 0; dt < 4; ++dt) {
        bf16x8 vb = *(const bf16x8*)&Vs[sw(dt * 16 + l16, koff)];
        o[dt] = __builtin_amdgcn_mfma_f32_16x16x32_bf16(pa, vb, o[dt], 0, 0, 0);
      }
      o[4] = __builtin_amdgcn_mfma_f32_16x16x32_bf16(pa, ones, o[4], 0, 0, 0);
    }
    __syncthreads();   // protect Ks/Vs before next tile's staging
  }

  #pragma unroll
  for (int r = 0; r < 4; ++r) {
    float inv = 1.f / o[4][r];
    int gi = i0 + w * 16 + lh * 4 + r;
    #pragma unroll
    for (int dt = 0; dt < 4; ++dt)
      attnout[((size_t)bb * 1024 + gi) * 512 + hh * 64 + dt * 16 + l16] = f2bf(o[dt][r] * inv);
  }
}

extern "C" void kernel_launch(void* const* d_in, const int* in_sizes, int n_in,
                              void* d_out, int out_size, void* d_ws, size_t ws_size,
                              hipStream_t stream) {
  const float* x     = (const float*)d_in[0];
  const float* gamma = (const float*)d_in[1];
  const float* w_qkv = (const float*)d_in[2];
  const float* w_out = (const float*)d_in[3];
  const float* cw0   = (const float*)d_in[4];
  const float* cb0   = (const float*)d_in[5];
  const float* cw1   = (const float*)d_in[6];
  const float* cb1   = (const float*)d_in[7];
  const float* cw2   = (const float*)d_in[8];
  const float* cb2   = (const float*)d_in[9];
  float* out = (float*)d_out;

  char* ws = (char*)d_ws;
  unsigned short* xnT   = (unsigned short*)(ws + 0);          // 8 MB
  unsigned short* wqb   = (unsigned short*)(ws + 8388608);    // 1.5 MB
  unsigned short* wob   = (unsigned short*)(ws + 9961472);    // 0.5 MB
  unsigned short* qT    = (unsigned short*)(ws + 10485760);   // 8 MB
  unsigned short* kT    = (unsigned short*)(ws + 18874368);   // 8 MB
  unsigned short* vB    = (unsigned short*)(ws + 27262976);   // 8 MB
  float*          table = (float*)(ws + 35651584);            // 128 KB
  unsigned short* biasP = (unsigned short*)(ws + 35782656);   // 16 MB
  unsigned short* aout  = (unsigned short*)(ws + 52559872);   // 8 MB

  prep_weights<<<3072, 256, 0, stream>>>(w_qkv, w_out, wqb, wob);
  cpb_table<<<3969, 128, 0, stream>>>(cw0, cb0, cw1, cb1, cw2, cb2, table);
  bias_expand<<<32768, 256, 0, stream>>>(table, biasP);
  ln_kernel<<<256, 256, 0, stream>>>(x, gamma, xnT);
  gemm_bt<0><<<dim3(64, 12), 256, 0, stream>>>(wqb, xnT, qT, kT, vB, nullptr, nullptr);
  attn_kernel<<<dim3(16, 64), 256, 0, stream>>>(qT, kT, vB, biasP, aout);
  gemm_bt<1><<<dim3(64, 4), 256, 0, stream>>>(wob, aout, nullptr, nullptr, nullptr, x, out);
}